// Round 4
// baseline (5524.312 us; speedup 1.0000x reference)
//
#include <hip/hip_runtime.h>
#include <math.h>

// BiLSTM B=64, S=512, I=H=512, fp32 in/out.
// Gate order f,g,i,o:  c = c*sig(f) + tanh(g)*sig(i); h = sig(o)*tanh(c)
// mask all-ones => lengths==S, h_f = fwd[S-1], h_b = bwd[0].
//
// Round-6 design: persistent kernel, point-to-point coherence, hop-overlap schedule.
//   Per-step critical path is ~4 coherence-point round trips (h-store ack, flag
//   propagate, poll, h-load) at ~1.5-2k cy each. This round hides two of them:
//   - wave 3 alone runs the producer chain (pack -> sc0 sc1 store -> vmcnt ack ->
//     flag store) while waves 0-2 stage x(t+1) from HBM (overlap, not sequence).
//   - consumer tail: x-MFMA half1 | poll | issue h-prefetch | x-MFMA half2 —
//     poll hides under half1, h-load RTT hides under half2. h fragments are
//     loop-carried prefetch consumed at the next iteration's vmcnt(16)/vmcnt(0).
//   - out stores issue inside combine (ack during x-stage; poll never drains them).
//   - v_cvt_pk_bf16_f32 packing for x staging (2 VALU + 1 ds_write_b64 per float4)
//     and h pack.
//   Sync protocol unchanged from round 5 (proven): per-group 32-flag array,
//   monotonic epochs, parity-double-buffered h ring, watchdog on the spin.

#define Sd 512
#define Bd 64
#define Hd 512
#define TWO_H 1024

typedef __attribute__((ext_vector_type(8))) short bf16x8;
typedef __attribute__((ext_vector_type(4))) float f32x4;

// ws layout (bytes)
#define UWT_OFF   0u          // bf16 [2][128][32][64][8]  = 8,388,608 B
#define BIAS_OFF  8388608u    // f32  [2][2048]            = 16,384 B
#define HBF_OFF   8404992u    // bf16 [2p][2d][4mt][16kb][64][8] = 262,144 B
#define FLG_OFF   8667136u    // u32  [4 groups][64] flags = 1,024 B

__device__ __forceinline__ unsigned short f2bf(float f) {
    unsigned u = __float_as_uint(f);
    u += 0x7fffu + ((u >> 16) & 1u);   // round-to-nearest-even
    return (unsigned short)(u >> 16);
}
__device__ __forceinline__ float sigmoidf_(float v) { return 1.0f / (1.0f + __expf(-v)); }
__device__ __forceinline__ float tanhf_(float v) {
    const float e = __expf(2.0f * v);  // exact at +/-inf
    return 1.0f - 2.0f / (e + 1.0f);
}
// packed f32x2 -> bf16x2 (RTNE), gfx950 has no builtin (m240) -> inline asm
__device__ __forceinline__ unsigned cvt_pk_bf16(float lo, float hi) {
    unsigned r;
    asm("v_cvt_pk_bf16_f32 %0, %1, %2" : "=v"(r) : "v"(lo), "v"(hi));
    return r;
}

// 4 coherence-point 16B loads off one base (kb stride = 64 lanes * 16B = 1024B)
#define LDH4(d0, d1, d2, d3, base)                                          \
    asm volatile("global_load_dwordx4 %0, %4, off sc0 sc1\n\t"              \
                 "global_load_dwordx4 %1, %4, off offset:1024 sc0 sc1\n\t"  \
                 "global_load_dwordx4 %2, %4, off offset:2048 sc0 sc1\n\t"  \
                 "global_load_dwordx4 %3, %4, off offset:3072 sc0 sc1"      \
                 : "=&v"(d0), "=&v"(d1), "=&v"(d2), "=&v"(d3)               \
                 : "v"(base))

// ---------------- prep: weights -> swizzled bf16 B-operand layout ----------------
__global__ __launch_bounds__(256) void prep_weights(
    const float* __restrict__ U_f, const float* __restrict__ W_f,
    const float* __restrict__ U_b, const float* __restrict__ W_b,
    unsigned short* __restrict__ uwt)
{
    const unsigned i = blockIdx.x * 256u + threadIdx.x;   // 524,288 threads
    const int h   = i & 511;
    const int k8  = (i >> 9) & 63;
    const int g   = (i >> 15) & 3;
    const int mat = (i >> 17) & 1;
    const int d   = (i >> 18) & 1;

    const float* src = mat ? (d ? W_b : W_f) : (d ? U_b : U_f);
    src += (size_t)g * Hd * Hd + (size_t)(k8 * 8) * Hd + h;

    const int n    = h * 4 + g;                      // gate-interleaved column
    const int nt   = n >> 4;
    const int lane = (n & 15) + ((mat * 64 + k8) & 3) * 16;
    const int kb   = mat * 16 + (k8 >> 2);

    bf16x8 v;
    #pragma unroll
    for (int j = 0; j < 8; ++j)
        v[j] = (short)f2bf(src[(size_t)j * Hd]);

    ((bf16x8*)uwt)[((d * 128 + nt) * 32 + kb) * 64 + lane] = v;
}

// ---------------- prep: zero h ring + flags, fill bias ----------------
__global__ __launch_bounds__(256) void prep_misc(
    const float* __restrict__ b_f, const float* __restrict__ b_b,
    unsigned char* __restrict__ ws)
{
    const unsigned i = blockIdx.x * 256u + threadIdx.x;   // 16,384 threads
    ((int4*)(ws + HBF_OFF))[i] = make_int4(0, 0, 0, 0);
    if (i < 4096) {
        const int d = i >> 11;
        const int n = i & 2047;
        const int g = n & 3;
        const int h = n >> 2;
        ((float*)(ws + BIAS_OFF))[i] = (d ? b_b : b_f)[g * Hd + h];
    }
    if (i < 256) ((unsigned*)(ws + FLG_OFF))[i] = 0u;
}

// ---------------- persistent BiLSTM ----------------
__global__ __launch_bounds__(256, 1) void lstm_persist(
    const float* __restrict__ x,          // [B,S,I] fp32
    unsigned char* __restrict__ ws,
    float* __restrict__ out)              // [S,B,2H] ++ h_f[B,H] ++ h_b[B,H]
{
    const int blk   = blockIdx.x;         // 128 blocks
    const int g     = blk & 3;            // sync group = (d, mhalf)
    const int d     = g & 1;
    const int mhalf = (g >> 1) & 1;
    const int ng    = blk >> 2;           // 0..31, 64-col group
    const int tid   = threadIdx.x;
    const int wid   = tid >> 6;
    const int lane  = tid & 63;

    const bf16x8* uwt_v = (const bf16x8*)(ws + UWT_OFF);
    bf16x8*       hbf_w = (bf16x8*)(ws + HBF_OFF);
    const float*  biasp = (const float*)(ws + BIAS_OFF);
    unsigned*     flg   = (unsigned*)(ws + FLG_OFF) + (size_t)g * 64;

    __shared__ __align__(16) short xs[32 * 520];   // x bf16, row pad +8
    __shared__ __align__(16) float gbuf[32 * 64];  // preacts
    __shared__ float hbuf[32 * 16];                // new h fp32

    const int nt  = ng * 4 + wid;         // this wave's n-tile (16 cols)
    const int mt0 = mhalf * 2;

    // ---- hoist this wave's whole B slice (K=1024 x N=16) into regs/AGPRs ----
    bf16x8 Bfrag[32];
    {
        const bf16x8* Bp = uwt_v + (size_t)((d * 128 + nt) * 32) * 64 + lane;
        #pragma unroll
        for (int kb = 0; kb < 32; ++kb) Bfrag[kb] = Bp[(size_t)kb * 64];
    }

    // ---- per-thread bias (cols j = jloc*4+gate; same for both cells) ----
    const int jloc = tid & 15;
    const int mloc = tid >> 4;            // 0..15 (cell rows mloc and mloc+16)
    const float* bias = biasp + d * 2048 + ng * 64 + jloc * 4;
    const float bf_ = bias[0], bg_ = bias[1], bi_ = bias[2], bo_ = bias[3];

    float c0 = 0.f, c1 = 0.f;             // c-state in registers
    const float4* x4 = (const float4*)x;

    const int r0 = lane & 15, q = lane >> 4;   // x A-fragment addressing
    const bf16x8* xv = (const bf16x8*)xs;

    // ---- prologue: stage x(0) (all threads), x-part preacts, prefetch h(p=0) ----
    f32x4 xacc0 = {0.f, 0.f, 0.f, 0.f};
    f32x4 xacc1 = {0.f, 0.f, 0.f, 0.f};
    {
        const int t0 = d ? (Sd - 1) : 0;
        for (int i = tid; i < 32 * 128; i += 256) {
            const int m  = i >> 7;
            const int c4 = i & 127;
            const int b  = mhalf * 32 + m;
            const float4 v = x4[((size_t)b * Sd + t0) * 128 + c4];
            short* p = xs + m * 520 + c4 * 4;
            *(uint2*)p = make_uint2(cvt_pk_bf16(v.x, v.y), cvt_pk_bf16(v.z, v.w));
        }
    }
    __syncthreads();
    #pragma unroll
    for (int kb2 = 0; kb2 < 16; ++kb2) {
        const bf16x8 bfrag = Bfrag[16 + kb2];
        const bf16x8 a0 = xv[r0 * 65 + kb2 * 4 + q];
        const bf16x8 a1 = xv[(r0 + 16) * 65 + kb2 * 4 + q];
        xacc0 = __builtin_amdgcn_mfma_f32_16x16x32_bf16(a0, bfrag, xacc0, 0, 0, 0);
        xacc1 = __builtin_amdgcn_mfma_f32_16x16x32_bf16(a1, bfrag, xacc1, 0, 0, 0);
    }

    // loop-carried h A-fragment prefetch registers
    bf16x8 A0[16], A1[16];
    {
        const unsigned char* hb = ws + HBF_OFF
            + ((size_t)(((0 * 2 + d) * 4 + mt0) * 16) * 64 + lane) * 16;
        LDH4(A0[0],  A0[1],  A0[2],  A0[3],  hb);
        LDH4(A0[4],  A0[5],  A0[6],  A0[7],  hb + 4096);
        LDH4(A0[8],  A0[9],  A0[10], A0[11], hb + 8192);
        LDH4(A0[12], A0[13], A0[14], A0[15], hb + 12288);
        LDH4(A1[0],  A1[1],  A1[2],  A1[3],  hb + 16384);
        LDH4(A1[4],  A1[5],  A1[6],  A1[7],  hb + 20480);
        LDH4(A1[8],  A1[9],  A1[10], A1[11], hb + 24576);
        LDH4(A1[12], A1[13], A1[14], A1[15], hb + 28672);
    }

    for (int t = 0; t < Sd; ++t) {
        const int t_orig = d ? (Sd - 1 - t) : t;
        const int p1 = (t & 1) ^ 1;       // write parity

        // ---- h-part MFMAs (prefetched A); A1 latency hides under acc0 chain ----
        f32x4 acc0 = xacc0, acc1 = xacc1;
        asm volatile("s_waitcnt vmcnt(16)" ::: "memory");   // A0 ready (in-order)
        __builtin_amdgcn_sched_barrier(0);
        #pragma unroll
        for (int kb = 0; kb < 16; ++kb)
            acc0 = __builtin_amdgcn_mfma_f32_16x16x32_bf16(A0[kb], Bfrag[kb], acc0, 0, 0, 0);
        __builtin_amdgcn_sched_barrier(0);
        asm volatile("s_waitcnt vmcnt(0)" ::: "memory");    // A1 ready
        __builtin_amdgcn_sched_barrier(0);
        #pragma unroll
        for (int kb = 0; kb < 16; ++kb)
            acc1 = __builtin_amdgcn_mfma_f32_16x16x32_bf16(A1[kb], Bfrag[kb], acc1, 0, 0, 0);

        // ---- scatter preacts to LDS (C/D: m=(lane>>4)*4+r, n=lane&15) ----
        {
            const int nl = wid * 16 + (lane & 15);
            const int mr = (lane >> 4) * 4;
            #pragma unroll
            for (int r = 0; r < 4; ++r) gbuf[(mr + r) * 64 + nl] = acc0[r];
            #pragma unroll
            for (int r = 0; r < 4; ++r) gbuf[(16 + mr + r) * 64 + nl] = acc1[r];
        }
        __syncthreads();

        // ---- combine + output stores (out acks overlap the rest of the step) ----
        {
            const f32x4 ga = *(const f32x4*)&gbuf[mloc * 64 + jloc * 4];
            const f32x4 gb = *(const f32x4*)&gbuf[(mloc + 16) * 64 + jloc * 4];
            c0 = c0 * sigmoidf_(ga[0] + bf_) + tanhf_(ga[1] + bg_) * sigmoidf_(ga[2] + bi_);
            const float h0c = sigmoidf_(ga[3] + bo_) * tanhf_(c0);
            c1 = c1 * sigmoidf_(gb[0] + bf_) + tanhf_(gb[1] + bg_) * sigmoidf_(gb[2] + bi_);
            const float h1c = sigmoidf_(gb[3] + bo_) * tanhf_(c1);
            hbuf[mloc * 16 + jloc] = h0c;
            hbuf[(mloc + 16) * 16 + jloc] = h1c;

            const int b0 = mhalf * 32 + mloc;
            const int jg = ng * 16 + jloc;
            float* ob = out + (size_t)d * Hd + jg;
            __builtin_nontemporal_store(h0c, ob + ((size_t)t_orig * Bd + b0) * TWO_H);
            __builtin_nontemporal_store(h1c, ob + ((size_t)t_orig * Bd + b0 + 16) * TWO_H);
            if (t == Sd - 1) {
                float* hf = out + (size_t)Sd * Bd * TWO_H + (size_t)d * Bd * Hd + jg;
                hf[(size_t)b0 * Hd] = h0c;
                hf[(size_t)(b0 + 16) * Hd] = h1c;
            }
        }
        __syncthreads();

        if (t == Sd - 1) break;

        // ---- PRODUCER (wave 3): pack h -> coherent store -> ack -> flag ----
        // ---- CONSUMER prep (waves 0-2): stage x(t+1) HBM -> LDS (overlapped) ----
        if (wid == 3) {
            const int l    = tid - 192;
            const int ml2  = l >> 1;
            const int jh   = l & 1;
            const int b    = mhalf * 32 + ml2;
            const int jb   = ng * 16 + jh * 8;        // 8-aligned
            const int kb   = jb >> 5;
            const int lq   = (jb >> 3) & 3;
            const int lh   = (b & 15) + lq * 16;
            const int mt   = b >> 4;
            const float* hp4 = &hbuf[ml2 * 16 + jh * 8];
            bf16x8 v;
            unsigned* vu = (unsigned*)&v;
            vu[0] = cvt_pk_bf16(hp4[0], hp4[1]);
            vu[1] = cvt_pk_bf16(hp4[2], hp4[3]);
            vu[2] = cvt_pk_bf16(hp4[4], hp4[5]);
            vu[3] = cvt_pk_bf16(hp4[6], hp4[7]);
            bf16x8* hp = hbf_w + (size_t)(((p1 * 2 + d) * 4 + mt) * 16 + kb) * 64 + lh;
            asm volatile("global_store_dwordx4 %0, %1, off sc0 sc1"
                         :: "v"(hp), "v"(v) : "memory");
            asm volatile("s_waitcnt vmcnt(0)" ::: "memory");   // h acked at L3
            if (tid == 192) {
                unsigned* fp = flg + ng;
                const unsigned fv = (unsigned)(t + 1);
                asm volatile("global_store_dword %0, %1, off sc0 sc1"
                             :: "v"(fp), "v"(fv) : "memory");
            }
        } else {
            const int tn = d ? (Sd - 2 - t) : (t + 1);
            for (int i = tid; i < 32 * 128; i += 192) {
                const int m  = i >> 7;
                const int c4 = i & 127;
                const int b  = mhalf * 32 + m;
                const float4 v = x4[((size_t)b * Sd + tn) * 128 + c4];
                short* p = xs + m * 520 + c4 * 4;
                *(uint2*)p = make_uint2(cvt_pk_bf16(v.x, v.y), cvt_pk_bf16(v.z, v.w));
            }
        }
        __syncthreads();

        // ---- x-MFMA half 1 (hides flag propagation / poll alignment) ----
        xacc0 = (f32x4){0.f, 0.f, 0.f, 0.f};
        xacc1 = (f32x4){0.f, 0.f, 0.f, 0.f};
        #pragma unroll
        for (int kb2 = 0; kb2 < 8; ++kb2) {
            const bf16x8 bfrag = Bfrag[16 + kb2];
            const bf16x8 a0 = xv[r0 * 65 + kb2 * 4 + q];
            const bf16x8 a1 = xv[(r0 + 16) * 65 + kb2 * 4 + q];
            xacc0 = __builtin_amdgcn_mfma_f32_16x16x32_bf16(a0, bfrag, xacc0, 0, 0, 0);
            xacc1 = __builtin_amdgcn_mfma_f32_16x16x32_bf16(a1, bfrag, xacc1, 0, 0, 0);
        }

        // ---- poll: all waves, all 32 flags in one load + ballot, watchdog ----
        {
            const unsigned tgt = (unsigned)(t + 1);
            const unsigned* fp = flg + (lane & 31);
            int guard = 0;
            for (;;) {
                unsigned v;
                asm volatile("global_load_dword %0, %1, off sc0 sc1\n\t"
                             "s_waitcnt vmcnt(0)"
                             : "=v"(v) : "v"(fp) : "memory");
                if (__ballot(v >= tgt) == ~0ull) break;
                __builtin_amdgcn_s_sleep(2);
                if (++guard > (1 << 15)) break;   // fail loud, never wedge
            }
            __builtin_amdgcn_sched_barrier(0);
        }

        // ---- issue h(t+1) prefetch (no wait; consumed next iteration) ----
        {
            const unsigned char* hb = ws + HBF_OFF
                + ((size_t)(((p1 * 2 + d) * 4 + mt0) * 16) * 64 + lane) * 16;
            LDH4(A0[0],  A0[1],  A0[2],  A0[3],  hb);
            LDH4(A0[4],  A0[5],  A0[6],  A0[7],  hb + 4096);
            LDH4(A0[8],  A0[9],  A0[10], A0[11], hb + 8192);
            LDH4(A0[12], A0[13], A0[14], A0[15], hb + 12288);
            LDH4(A1[0],  A1[1],  A1[2],  A1[3],  hb + 16384);
            LDH4(A1[4],  A1[5],  A1[6],  A1[7],  hb + 20480);
            LDH4(A1[8],  A1[9],  A1[10], A1[11], hb + 24576);
            LDH4(A1[12], A1[13], A1[14], A1[15], hb + 28672);
        }

        // ---- x-MFMA half 2 (hides h-load round trip) ----
        #pragma unroll
        for (int kb2 = 8; kb2 < 16; ++kb2) {
            const bf16x8 bfrag = Bfrag[16 + kb2];
            const bf16x8 a0 = xv[r0 * 65 + kb2 * 4 + q];
            const bf16x8 a1 = xv[(r0 + 16) * 65 + kb2 * 4 + q];
            xacc0 = __builtin_amdgcn_mfma_f32_16x16x32_bf16(a0, bfrag, xacc0, 0, 0, 0);
            xacc1 = __builtin_amdgcn_mfma_f32_16x16x32_bf16(a1, bfrag, xacc1, 0, 0, 0);
        }
        // intra-block LDS hazards for next iter are covered by its barriers.
    }
}

extern "C" void kernel_launch(void* const* d_in, const int* in_sizes, int n_in,
                              void* d_out, int out_size, void* d_ws, size_t ws_size,
                              hipStream_t stream) {
    const float* x   = (const float*)d_in[0];
    // d_in[1] = mask: all-ones by construction; unused.
    const float* U_f = (const float*)d_in[2];
    const float* W_f = (const float*)d_in[3];
    const float* b_f = (const float*)d_in[4];
    const float* U_b = (const float*)d_in[5];
    const float* W_b = (const float*)d_in[6];
    const float* b_b = (const float*)d_in[7];
    float* out = (float*)d_out;
    unsigned char* ws = (unsigned char*)d_ws;

    prep_weights<<<2048, 256, 0, stream>>>(U_f, W_f, U_b, W_b,
                                           (unsigned short*)(ws + UWT_OFF));
    prep_misc<<<64, 256, 0, stream>>>(b_f, b_b, ws);
    lstm_persist<<<128, 256, 0, stream>>>(x, ws, out);
}

// Round 5
// 4586.869 us; speedup vs baseline: 1.2044x; 1.2044x over previous
//
#include <hip/hip_runtime.h>
#include <math.h>

// BiLSTM B=64, S=512, I=H=512, fp32 in/out.
// Gate order f,g,i,o:  c = c*sig(f) + tanh(g)*sig(i); h = sig(o)*tanh(c)
// mask all-ones => lengths==S, h_f = fwd[S-1], h_b = bwd[0].
//
// Round-7 design: persistent kernel; round-3 sync protocol; de-duplicated h path.
//   Round-3 waste: every wave of every block loaded the SAME 32KB h slab with
//   sc0sc1 (L2-bypass) loads -> 16MB/step of coherent L3 traffic + 512 spinning
//   waves on the flag lines => contention-inflated RTTs (6.95us/step).
//   This round:
//   - h slab staged ONCE per block into LDS (256 thr x 8 x 16B coherent loads ->
//     ds_write_b128); all 4 waves read A-fragments from LDS. 4x less coherent
//     read traffic; per-wave vmcnt dance gone; ~128 VGPRs freed.
//   - poll by wave 0 only + __syncthreads broadcast (4x less flag traffic).
//   - producer chain exactly round-3: pack -> sc0sc1 store -> vmcnt(0) -> flag,
//     BEFORE any out stores (round-4 regression: out stores contaminated the ack).
//   - sync protocol (parity ring, 32-flag array, epochs, watchdog) unchanged
//     from the proven round-3 kernel.

#define Sd 512
#define Bd 64
#define Hd 512
#define TWO_H 1024

typedef __attribute__((ext_vector_type(8))) short bf16x8;
typedef __attribute__((ext_vector_type(4))) float f32x4;

// ws layout (bytes)
#define UWT_OFF   0u          // bf16 [2][128][32][64][8]  = 8,388,608 B
#define BIAS_OFF  8388608u    // f32  [2][2048]            = 16,384 B
#define HBF_OFF   8404992u    // bf16 [2p][2d][4mt][16kb][64][8] = 262,144 B
#define FLG_OFF   8667136u    // u32  [4 groups][64] flags = 1,024 B

__device__ __forceinline__ unsigned short f2bf(float f) {
    unsigned u = __float_as_uint(f);
    u += 0x7fffu + ((u >> 16) & 1u);   // round-to-nearest-even
    return (unsigned short)(u >> 16);
}
__device__ __forceinline__ float sigmoidf_(float v) { return 1.0f / (1.0f + __expf(-v)); }
__device__ __forceinline__ float tanhf_(float v) {
    const float e = __expf(2.0f * v);  // exact at +/-inf
    return 1.0f - 2.0f / (e + 1.0f);
}
// packed f32x2 -> bf16x2 (RTNE); no builtin on gfx950 -> inline asm
__device__ __forceinline__ unsigned cvt_pk_bf16(float lo, float hi) {
    unsigned r;
    asm("v_cvt_pk_bf16_f32 %0, %1, %2" : "=v"(r) : "v"(lo), "v"(hi));
    return r;
}

// one coherence-point 16B load
#define LDC(dst, ptr)                                                   \
    asm volatile("global_load_dwordx4 %0, %1, off sc0 sc1"              \
                 : "=&v"(dst) : "v"(ptr))

// ---------------- prep: weights -> swizzled bf16 B-operand layout ----------------
__global__ __launch_bounds__(256) void prep_weights(
    const float* __restrict__ U_f, const float* __restrict__ W_f,
    const float* __restrict__ U_b, const float* __restrict__ W_b,
    unsigned short* __restrict__ uwt)
{
    const unsigned i = blockIdx.x * 256u + threadIdx.x;   // 524,288 threads
    const int h   = i & 511;
    const int k8  = (i >> 9) & 63;
    const int g   = (i >> 15) & 3;
    const int mat = (i >> 17) & 1;
    const int d   = (i >> 18) & 1;

    const float* src = mat ? (d ? W_b : W_f) : (d ? U_b : U_f);
    src += (size_t)g * Hd * Hd + (size_t)(k8 * 8) * Hd + h;

    const int n    = h * 4 + g;                      // gate-interleaved column
    const int nt   = n >> 4;
    const int lane = (n & 15) + ((mat * 64 + k8) & 3) * 16;
    const int kb   = mat * 16 + (k8 >> 2);

    bf16x8 v;
    #pragma unroll
    for (int j = 0; j < 8; ++j)
        v[j] = (short)f2bf(src[(size_t)j * Hd]);

    ((bf16x8*)uwt)[((d * 128 + nt) * 32 + kb) * 64 + lane] = v;
}

// ---------------- prep: zero h ring + flags, fill bias ----------------
__global__ __launch_bounds__(256) void prep_misc(
    const float* __restrict__ b_f, const float* __restrict__ b_b,
    unsigned char* __restrict__ ws)
{
    const unsigned i = blockIdx.x * 256u + threadIdx.x;   // 16,384 threads
    ((int4*)(ws + HBF_OFF))[i] = make_int4(0, 0, 0, 0);
    if (i < 4096) {
        const int d = i >> 11;
        const int n = i & 2047;
        const int g = n & 3;
        const int h = n >> 2;
        ((float*)(ws + BIAS_OFF))[i] = (d ? b_b : b_f)[g * Hd + h];
    }
    if (i < 256) ((unsigned*)(ws + FLG_OFF))[i] = 0u;
}

// ---------------- persistent BiLSTM ----------------
__global__ __launch_bounds__(256, 1) void lstm_persist(
    const float* __restrict__ x,          // [B,S,I] fp32
    unsigned char* __restrict__ ws,
    float* __restrict__ out)              // [S,B,2H] ++ h_f[B,H] ++ h_b[B,H]
{
    const int blk   = blockIdx.x;         // 128 blocks
    const int g     = blk & 3;            // sync group = (d, mhalf)
    const int d     = g & 1;
    const int mhalf = (g >> 1) & 1;
    const int ng    = blk >> 2;           // 0..31, 64-col group
    const int tid   = threadIdx.x;
    const int wid   = tid >> 6;
    const int lane  = tid & 63;

    const bf16x8* uwt_v = (const bf16x8*)(ws + UWT_OFF);
    bf16x8*       hbf_w = (bf16x8*)(ws + HBF_OFF);
    const float*  biasp = (const float*)(ws + BIAS_OFF);
    unsigned*     flg   = (unsigned*)(ws + FLG_OFF) + (size_t)g * 64;

    __shared__ __align__(16) short xs[32 * 520];   // x bf16, row pad +8 (33,280 B)
    __shared__ __align__(16) float gbuf[32 * 64];  // preacts (8,192 B)
    __shared__ float hbuf[32 * 16];                // new h fp32 (2,048 B)
    __shared__ bf16x8 hstage[2048];                // h slab stage (32,768 B)

    const int nt  = ng * 4 + wid;         // this wave's n-tile (16 cols)
    const int mt0 = mhalf * 2;

    // ---- hoist this wave's whole B slice (K=1024 x N=16) into regs/AGPRs ----
    bf16x8 Bfrag[32];
    {
        const bf16x8* Bp = uwt_v + (size_t)((d * 128 + nt) * 32) * 64 + lane;
        #pragma unroll
        for (int kb = 0; kb < 32; ++kb) Bfrag[kb] = Bp[(size_t)kb * 64];
    }

    // ---- per-thread bias (cols j = jloc*4+gate; same for both cells) ----
    const int jloc = tid & 15;
    const int mloc = tid >> 4;            // 0..15 (cell rows mloc and mloc+16)
    const float* bias = biasp + d * 2048 + ng * 64 + jloc * 4;
    const float bf_ = bias[0], bg_ = bias[1], bi_ = bias[2], bo_ = bias[3];

    float c0 = 0.f, c1 = 0.f;             // c-state in registers
    const float4* x4 = (const float4*)x;

    const int r0 = lane & 15, q = lane >> 4;   // x A-fragment addressing
    const bf16x8* xv = (const bf16x8*)xs;

    // ---- prologue: stage x(0), x-part preacts ----
    f32x4 xacc0 = {0.f, 0.f, 0.f, 0.f};
    f32x4 xacc1 = {0.f, 0.f, 0.f, 0.f};
    {
        const int t0 = d ? (Sd - 1) : 0;
        for (int i = tid; i < 32 * 128; i += 256) {
            const int m  = i >> 7;
            const int c4 = i & 127;
            const int b  = mhalf * 32 + m;
            const float4 v = x4[((size_t)b * Sd + t0) * 128 + c4];
            short* p = xs + m * 520 + c4 * 4;
            *(uint2*)p = make_uint2(cvt_pk_bf16(v.x, v.y), cvt_pk_bf16(v.z, v.w));
        }
    }
    __syncthreads();
    #pragma unroll
    for (int kb2 = 0; kb2 < 16; ++kb2) {
        const bf16x8 bfrag = Bfrag[16 + kb2];
        const bf16x8 a0 = xv[r0 * 65 + kb2 * 4 + q];
        const bf16x8 a1 = xv[(r0 + 16) * 65 + kb2 * 4 + q];
        xacc0 = __builtin_amdgcn_mfma_f32_16x16x32_bf16(a0, bfrag, xacc0, 0, 0, 0);
        xacc1 = __builtin_amdgcn_mfma_f32_16x16x32_bf16(a1, bfrag, xacc1, 0, 0, 0);
    }

    for (int t = 0; t < Sd; ++t) {
        const int t_orig = d ? (Sd - 1 - t) : t;
        const int p0 = t & 1;             // read parity (t=0: ring zeroed)
        const int p1 = p0 ^ 1;            // write parity

        // ---- stage h slab (32KB, shared by all 4 waves) into LDS, ONCE ----
        // chunk c = j*256 + tid; src and LDS share the ring's linear layout.
        {
            const unsigned char* gs = ws + HBF_OFF
                + ((size_t)(((p0 * 2 + d) * 4 + mt0) * 16) * 64) * 16 + (size_t)tid * 16;
            bf16x8 st[8];
            #pragma unroll
            for (int j = 0; j < 8; ++j) LDC(st[j], gs + (size_t)j * 4096);
            asm volatile("s_waitcnt vmcnt(0)" ::: "memory");
            __builtin_amdgcn_sched_barrier(0);
            #pragma unroll
            for (int j = 0; j < 8; ++j) hstage[j * 256 + tid] = st[j];
        }
        __syncthreads();

        // ---- h-part MFMAs from LDS (A0 = mt0 slab, A1 = mt0+1 slab) ----
        f32x4 acc0 = xacc0, acc1 = xacc1;
        #pragma unroll
        for (int kb = 0; kb < 16; ++kb) {
            acc0 = __builtin_amdgcn_mfma_f32_16x16x32_bf16(hstage[kb * 64 + lane],
                                                           Bfrag[kb], acc0, 0, 0, 0);
            acc1 = __builtin_amdgcn_mfma_f32_16x16x32_bf16(hstage[1024 + kb * 64 + lane],
                                                           Bfrag[kb], acc1, 0, 0, 0);
        }

        // ---- scatter preacts to LDS (C/D: m=(lane>>4)*4+r, n=lane&15) ----
        {
            const int nl = wid * 16 + (lane & 15);
            const int mr = (lane >> 4) * 4;
            #pragma unroll
            for (int r = 0; r < 4; ++r) gbuf[(mr + r) * 64 + nl] = acc0[r];
            #pragma unroll
            for (int r = 0; r < 4; ++r) gbuf[(16 + mr + r) * 64 + nl] = acc1[r];
        }
        __syncthreads();

        // ---- combine: activations + c/h update; 2 cells per thread ----
        float h0c, h1c;
        {
            const f32x4 ga = *(const f32x4*)&gbuf[mloc * 64 + jloc * 4];
            const f32x4 gb = *(const f32x4*)&gbuf[(mloc + 16) * 64 + jloc * 4];
            c0 = c0 * sigmoidf_(ga[0] + bf_) + tanhf_(ga[1] + bg_) * sigmoidf_(ga[2] + bi_);
            h0c = sigmoidf_(ga[3] + bo_) * tanhf_(c0);
            c1 = c1 * sigmoidf_(gb[0] + bf_) + tanhf_(gb[1] + bg_) * sigmoidf_(gb[2] + bi_);
            h1c = sigmoidf_(gb[3] + bo_) * tanhf_(c1);
            hbuf[mloc * 16 + jloc] = h0c;
            hbuf[(mloc + 16) * 16 + jloc] = h1c;
        }
        __syncthreads();

        if (t < Sd - 1) {
            // ---- producer (wave 0): pack -> coherent store -> ack -> flag ----
            // NOTHING else in wave 0's vmem queue here (round-4 lesson).
            if (tid < 64) {
                const int ml2 = tid >> 1;
                const int jh  = tid & 1;
                const int b   = mhalf * 32 + ml2;
                const int jb  = ng * 16 + jh * 8;        // 8-aligned
                const int kb  = jb >> 5;
                const int lq  = (jb >> 3) & 3;
                const int lh  = (b & 15) + lq * 16;
                const int mt  = b >> 4;
                const float* hp4 = &hbuf[ml2 * 16 + jh * 8];
                bf16x8 v;
                unsigned* vu = (unsigned*)&v;
                vu[0] = cvt_pk_bf16(hp4[0], hp4[1]);
                vu[1] = cvt_pk_bf16(hp4[2], hp4[3]);
                vu[2] = cvt_pk_bf16(hp4[4], hp4[5]);
                vu[3] = cvt_pk_bf16(hp4[6], hp4[7]);
                bf16x8* hp = hbf_w + (size_t)(((p1 * 2 + d) * 4 + mt) * 16 + kb) * 64 + lh;
                asm volatile("global_store_dwordx4 %0, %1, off sc0 sc1"
                             :: "v"(hp), "v"(v) : "memory");
                asm volatile("s_waitcnt vmcnt(0)" ::: "memory");   // h acked
                if (tid == 0) {
                    unsigned* fp = flg + ng;
                    const unsigned fv = (unsigned)(t + 1);
                    asm volatile("global_store_dword %0, %1, off sc0 sc1"
                                 :: "v"(fp), "v"(fv) : "memory");
                }
            }
        }

        // ---- output stores (after flag publish; off the sync critical path) ----
        {
            const int b0 = mhalf * 32 + mloc;
            const int jg = ng * 16 + jloc;
            float* ob = out + (size_t)d * Hd + jg;
            __builtin_nontemporal_store(h0c, ob + ((size_t)t_orig * Bd + b0) * TWO_H);
            __builtin_nontemporal_store(h1c, ob + ((size_t)t_orig * Bd + b0 + 16) * TWO_H);
            if (t == Sd - 1) {
                float* hf = out + (size_t)Sd * Bd * TWO_H + (size_t)d * Bd * Hd + jg;
                hf[(size_t)b0 * Hd] = h0c;
                hf[(size_t)(b0 + 16) * Hd] = h1c;
            }
        }

        if (t == Sd - 1) break;

        // ---- hidden in the flag-propagation window: stage x(t+1) ----
        {
            const int tn = d ? (Sd - 2 - t) : (t + 1);
            for (int i = tid; i < 32 * 128; i += 256) {
                const int m  = i >> 7;
                const int c4 = i & 127;
                const int b  = mhalf * 32 + m;
                const float4 v = x4[((size_t)b * Sd + tn) * 128 + c4];
                short* p = xs + m * 520 + c4 * 4;
                *(uint2*)p = make_uint2(cvt_pk_bf16(v.x, v.y), cvt_pk_bf16(v.z, v.w));
            }
        }
        __syncthreads();

        // ---- x-part MFMAs for t+1 ----
        xacc0 = (f32x4){0.f, 0.f, 0.f, 0.f};
        xacc1 = (f32x4){0.f, 0.f, 0.f, 0.f};
        #pragma unroll
        for (int kb2 = 0; kb2 < 16; ++kb2) {
            const bf16x8 bfrag = Bfrag[16 + kb2];
            const bf16x8 a0 = xv[r0 * 65 + kb2 * 4 + q];
            const bf16x8 a1 = xv[(r0 + 16) * 65 + kb2 * 4 + q];
            xacc0 = __builtin_amdgcn_mfma_f32_16x16x32_bf16(a0, bfrag, xacc0, 0, 0, 0);
            xacc1 = __builtin_amdgcn_mfma_f32_16x16x32_bf16(a1, bfrag, xacc1, 0, 0, 0);
        }

        // ---- poll (wave 0 only; 4x less flag traffic), then block-wide barrier ----
        if (wid == 0) {
            const unsigned tgt = (unsigned)(t + 1);
            const unsigned* fp = flg + (lane & 31);
            int guard = 0;
            for (;;) {
                unsigned v;
                asm volatile("global_load_dword %0, %1, off sc0 sc1\n\t"
                             "s_waitcnt vmcnt(0)"
                             : "=v"(v) : "v"(fp) : "memory");
                if (__ballot(v >= tgt) == ~0ull) break;
                __builtin_amdgcn_s_sleep(2);
                if (++guard > (1 << 15)) break;   // fail loud, never wedge
            }
            __builtin_amdgcn_sched_barrier(0);
        }
        __syncthreads();   // broadcast "ring readable" + protect hstage overwrite
    }
}

extern "C" void kernel_launch(void* const* d_in, const int* in_sizes, int n_in,
                              void* d_out, int out_size, void* d_ws, size_t ws_size,
                              hipStream_t stream) {
    const float* x   = (const float*)d_in[0];
    // d_in[1] = mask: all-ones by construction; unused.
    const float* U_f = (const float*)d_in[2];
    const float* W_f = (const float*)d_in[3];
    const float* b_f = (const float*)d_in[4];
    const float* U_b = (const float*)d_in[5];
    const float* W_b = (const float*)d_in[6];
    const float* b_b = (const float*)d_in[7];
    float* out = (float*)d_out;
    unsigned char* ws = (unsigned char*)d_ws;

    prep_weights<<<2048, 256, 0, stream>>>(U_f, W_f, U_b, W_b,
                                           (unsigned short*)(ws + UWT_OFF));
    prep_misc<<<64, 256, 0, stream>>>(b_f, b_b, ws);
    lstm_persist<<<128, 256, 0, stream>>>(x, ws, out);
}

// Round 6
// 2484.351 us; speedup vs baseline: 2.2236x; 1.8463x over previous
//
#include <hip/hip_runtime.h>
#include <math.h>

// BiLSTM B=64, S=512, I=H=512, fp32 in/out.
// Gate order f,g,i,o:  c = c*sig(f) + tanh(g)*sig(i); h = sig(o)*tanh(c)
// mask all-ones => lengths==S, h_f = fwd[S-1], h_b = bwd[0].
//
// Round-8 design: persistent kernel; round-3 sync protocol (best so far, 6.95us/step);
// serial-chain surgery:
//   1) x pre-converted to bf16 fragment-swizzled tiles ONCE (prep_x, 32MB in ws);
//      per step the tile arrives via global_load_lds issued at the TOP of the step
//      (zero VGPR, HBM latency + convert + LDS-write all leave the serial path).
//      Read swizzle (kb*4+q)^(m&7) keeps ds_read_b128 ~2-way (free).
//      Fallback (ws too small): round-3 in-loop convert staging. template<bool XT>.
//   2) raw s_barrier + targeted lgkmcnt(0) instead of __syncthreads (which drains
//      vmcnt(0) and would kill every prefetch crossing a barrier). Counted vmcnt:
//      top vmcnt(24)/(8) [32 h-loads older + 8 glds newer], tail vmcnt(32).
//   3) loop-carried h prefetch: tail = poll -> out-stores -> issue h(t+1) ->
//      vmcnt(32) -> barrier -> x-MFMA (x-MFMA hides part of the h RTT).
//   Producer chain (wave 0) stays pristine: pack -> sc0sc1 store -> vmcnt(0) ->
//   flag, nothing else in its vmem queue (round-4 lesson).

#define Sd 512
#define Bd 64
#define Hd 512
#define TWO_H 1024

typedef __attribute__((ext_vector_type(8))) short bf16x8;
typedef __attribute__((ext_vector_type(4))) float f32x4;

// ws layout (bytes)
#define UWT_OFF   0u          // bf16 [2][128][32][64][8]  = 8,388,608 B
#define BIAS_OFF  8388608u    // f32  [2][2048]            = 16,384 B
#define HBF_OFF   8404992u    // bf16 [2p][2d][4mt][16kb][64][8] = 262,144 B
#define FLG_OFF   8667136u    // u32  [4 groups][64] flags = 1,024 B
#define XT_OFF    8668160u    // bf16 tiles [2mh][512t][2048 frag][16B] = 33,554,432 B
#define WS_NEED   (XT_OFF + 33554432u)

__device__ __forceinline__ unsigned short f2bf(float f) {
    unsigned u = __float_as_uint(f);
    u += 0x7fffu + ((u >> 16) & 1u);   // round-to-nearest-even
    return (unsigned short)(u >> 16);
}
__device__ __forceinline__ float sigmoidf_(float v) { return 1.0f / (1.0f + __expf(-v)); }
__device__ __forceinline__ float tanhf_(float v) {
    const float e = __expf(2.0f * v);  // exact at +/-inf
    return 1.0f - 2.0f / (e + 1.0f);
}
__device__ __forceinline__ unsigned cvt_pk_bf16(float lo, float hi) {
    unsigned r;
    asm("v_cvt_pk_bf16_f32 %0, %1, %2" : "=v"(r) : "v"(lo), "v"(hi));
    return r;
}
__device__ __forceinline__ void gld_lds16(const void* g, void* l) {
    __builtin_amdgcn_global_load_lds(
        (const __attribute__((address_space(1))) void*)(g),
        (__attribute__((address_space(3))) void*)(l), 16, 0, 0);
}
__device__ __forceinline__ void raw_bar() {
    __builtin_amdgcn_sched_barrier(0);
    __builtin_amdgcn_s_barrier();
    __builtin_amdgcn_sched_barrier(0);
}
__device__ __forceinline__ void lgkm_bar() {
    asm volatile("s_waitcnt lgkmcnt(0)" ::: "memory");
    raw_bar();
}

// 4 coherence-point 16B loads off one base (kb stride = 64 lanes * 16B = 1024B)
#define LDH4(d0, d1, d2, d3, base)                                          \
    asm volatile("global_load_dwordx4 %0, %4, off sc0 sc1\n\t"              \
                 "global_load_dwordx4 %1, %4, off offset:1024 sc0 sc1\n\t"  \
                 "global_load_dwordx4 %2, %4, off offset:2048 sc0 sc1\n\t"  \
                 "global_load_dwordx4 %3, %4, off offset:3072 sc0 sc1"      \
                 : "=&v"(d0), "=&v"(d1), "=&v"(d2), "=&v"(d3)               \
                 : "v"(base))

// ---------------- prep: weights -> swizzled bf16 B-operand layout ----------------
__global__ __launch_bounds__(256) void prep_weights(
    const float* __restrict__ U_f, const float* __restrict__ W_f,
    const float* __restrict__ U_b, const float* __restrict__ W_b,
    unsigned short* __restrict__ uwt)
{
    const unsigned i = blockIdx.x * 256u + threadIdx.x;   // 524,288 threads
    const int h   = i & 511;
    const int k8  = (i >> 9) & 63;
    const int g   = (i >> 15) & 3;
    const int mat = (i >> 17) & 1;
    const int d   = (i >> 18) & 1;

    const float* src = mat ? (d ? W_b : W_f) : (d ? U_b : U_f);
    src += (size_t)g * Hd * Hd + (size_t)(k8 * 8) * Hd + h;

    const int n    = h * 4 + g;                      // gate-interleaved column
    const int nt   = n >> 4;
    const int lane = (n & 15) + ((mat * 64 + k8) & 3) * 16;
    const int kb   = mat * 16 + (k8 >> 2);

    bf16x8 v;
    #pragma unroll
    for (int j = 0; j < 8; ++j)
        v[j] = (short)f2bf(src[(size_t)j * Hd]);

    ((bf16x8*)uwt)[((d * 128 + nt) * 32 + kb) * 64 + lane] = v;
}

// ---------------- prep: x fp32 -> bf16 fragment-swizzled tiles ----------------
// tile (mh, t): 2048 fragments of 16B; fragment at unit v = m*64 + ((kb*4+q)^(m&7))
// holds x[b=mh*32+m][t][kb*32+q*8 .. +8) as bf16. Linear dest = gload_lds-ready.
__global__ __launch_bounds__(256) void prep_x(
    const float* __restrict__ x, unsigned short* __restrict__ xt)
{
    const unsigned i = blockIdx.x * 256u + threadIdx.x;   // 2,097,152 threads
    const int v  = i & 2047;
    const int t  = (i >> 11) & 511;
    const int mh = (i >> 20) & 1;
    const int m  = v >> 6;
    const int w  = (v & 63) ^ (m & 7);
    const int k0 = (w >> 2) * 32 + (w & 3) * 8;
    const int b  = mh * 32 + m;
    const float4* s = (const float4*)(x + ((size_t)b * Sd + t) * Hd + k0);
    const float4 u0 = s[0], u1 = s[1];
    bf16x8 o;
    unsigned* ou = (unsigned*)&o;
    ou[0] = cvt_pk_bf16(u0.x, u0.y); ou[1] = cvt_pk_bf16(u0.z, u0.w);
    ou[2] = cvt_pk_bf16(u1.x, u1.y); ou[3] = cvt_pk_bf16(u1.z, u1.w);
    ((bf16x8*)xt)[i] = o;
}

// ---------------- prep: zero h ring + flags, fill bias ----------------
__global__ __launch_bounds__(256) void prep_misc(
    const float* __restrict__ b_f, const float* __restrict__ b_b,
    unsigned char* __restrict__ ws)
{
    const unsigned i = blockIdx.x * 256u + threadIdx.x;   // 16,384 threads
    ((int4*)(ws + HBF_OFF))[i] = make_int4(0, 0, 0, 0);
    if (i < 4096) {
        const int d = i >> 11;
        const int n = i & 2047;
        const int g = n & 3;
        const int h = n >> 2;
        ((float*)(ws + BIAS_OFF))[i] = (d ? b_b : b_f)[g * Hd + h];
    }
    if (i < 256) ((unsigned*)(ws + FLG_OFF))[i] = 0u;
}

// ---------------- persistent BiLSTM ----------------
template<bool XT>
__global__ __launch_bounds__(256, 1) void lstm_persist(
    const float* __restrict__ x,          // [B,S,I] fp32
    unsigned char* __restrict__ ws,
    float* __restrict__ out)              // [S,B,2H] ++ h_f[B,H] ++ h_b[B,H]
{
    const int blk   = blockIdx.x;         // 128 blocks
    const int g     = blk & 3;            // sync group = (d, mhalf)
    const int d     = g & 1;
    const int mhalf = (g >> 1) & 1;
    const int ng    = blk >> 2;           // 0..31, 64-col group
    const int tid   = threadIdx.x;
    const int wid   = tid >> 6;
    const int lane  = tid & 63;

    const bf16x8* uwt_v = (const bf16x8*)(ws + UWT_OFF);
    bf16x8*       hbf_w = (bf16x8*)(ws + HBF_OFF);
    const float*  biasp = (const float*)(ws + BIAS_OFF);
    unsigned*     flg   = (unsigned*)(ws + FLG_OFF) + (size_t)g * 64;
    const char*   xt    = (const char*)(ws + XT_OFF);

    __shared__ __align__(16) short xs[16640];      // XT: 32KB linear; noXT: 32x520 padded
    __shared__ __align__(16) float gbuf[32 * 64];  // preacts
    __shared__ float hbuf[32 * 16];                // new h fp32

    const int nt  = ng * 4 + wid;         // this wave's n-tile (16 cols)
    const int mt0 = mhalf * 2;

    // ---- hoist this wave's whole B slice (K=1024 x N=16) into regs/AGPRs ----
    bf16x8 Bfrag[32];
    {
        const bf16x8* Bp = uwt_v + (size_t)((d * 128 + nt) * 32) * 64 + lane;
        #pragma unroll
        for (int kb = 0; kb < 32; ++kb) Bfrag[kb] = Bp[(size_t)kb * 64];
    }

    const int jloc = tid & 15;
    const int mloc = tid >> 4;
    const float* bias = biasp + d * 2048 + ng * 64 + jloc * 4;
    const float bf_ = bias[0], bg_ = bias[1], bi_ = bias[2], bo_ = bias[3];

    float c0 = 0.f, c1 = 0.f;
    const float4* x4 = (const float4*)x;
    const int r0 = lane & 15, q = lane >> 4, r07 = r0 & 7;
    const bf16x8* xv = (const bf16x8*)xs;
    char* xsb = (char*)xs;

    f32x4 xacc0, xacc1;
    bf16x8 A0[16], A1[16];

    // issue 8 global_load_lds (1KB each) for tile (mhalf, tn); wave-uniform LDS dest
    auto stage_x = [&](int tn) {
        const char* tb = xt + ((size_t)(mhalf * 512 + tn) * 2048) * 16;
        #pragma unroll
        for (int j = 0; j < 8; ++j) {
            const int chunk = wid * 8 + j;
            gld_lds16(tb + (size_t)chunk * 1024 + (size_t)lane * 16,
                      xsb + chunk * 1024);
        }
    };
    // round-3 fallback: fp32 load + cvt_pk + padded LDS store
    auto stage_x_conv = [&](int tn) {
        for (int i = tid; i < 32 * 128; i += 256) {
            const int m  = i >> 7;
            const int c4 = i & 127;
            const int b  = mhalf * 32 + m;
            const float4 v = x4[((size_t)b * Sd + tn) * 128 + c4];
            short* p = xs + m * 520 + c4 * 4;
            *(uint2*)p = make_uint2(cvt_pk_bf16(v.x, v.y), cvt_pk_bf16(v.z, v.w));
        }
    };
    auto xmfma = [&]() {
        xacc0 = (f32x4){0.f, 0.f, 0.f, 0.f};
        xacc1 = (f32x4){0.f, 0.f, 0.f, 0.f};
        #pragma unroll
        for (int kb2 = 0; kb2 < 16; ++kb2) {
            const bf16x8 bfrag = Bfrag[16 + kb2];
            int u0, u1;
            if constexpr (XT) { u0 = r0 * 64 + ((kb2 * 4 + q) ^ r07); u1 = u0 + 1024; }
            else              { u0 = r0 * 65 + kb2 * 4 + q;           u1 = u0 + 16 * 65; }
            const bf16x8 a0 = xv[u0];
            const bf16x8 a1 = xv[u1];
            xacc0 = __builtin_amdgcn_mfma_f32_16x16x32_bf16(a0, bfrag, xacc0, 0, 0, 0);
            xacc1 = __builtin_amdgcn_mfma_f32_16x16x32_bf16(a1, bfrag, xacc1, 0, 0, 0);
        }
    };
    auto issue_h = [&](int p) {
        const unsigned char* hb = ws + HBF_OFF
            + ((size_t)(((p * 2 + d) * 4 + mt0) * 16) * 64 + lane) * 16;
        LDH4(A0[0],  A0[1],  A0[2],  A0[3],  hb);
        LDH4(A0[4],  A0[5],  A0[6],  A0[7],  hb + 4096);
        LDH4(A0[8],  A0[9],  A0[10], A0[11], hb + 8192);
        LDH4(A0[12], A0[13], A0[14], A0[15], hb + 12288);
        LDH4(A1[0],  A1[1],  A1[2],  A1[3],  hb + 16384);
        LDH4(A1[4],  A1[5],  A1[6],  A1[7],  hb + 20480);
        LDH4(A1[8],  A1[9],  A1[10], A1[11], hb + 24576);
        LDH4(A1[12], A1[13], A1[14], A1[15], hb + 28672);
    };

    // ---- prologue: stage x(0), x-part preacts, issue h(0) loads (zeroed ring) ----
    {
        const int t0 = d ? (Sd - 1) : 0;
        if constexpr (XT) {
            stage_x(t0);
            asm volatile("s_waitcnt vmcnt(0)" ::: "memory");
        } else {
            stage_x_conv(t0);
        }
    }
    __syncthreads();
    xmfma();
    issue_h(0);

    for (int t = 0; t < Sd; ++t) {
        const int t_orig = d ? (Sd - 1 - t) : t;
        const int p1 = (t & 1) ^ 1;       // write parity

        // ---- top: issue x(t+1) gload_lds (XT); barrier guards xs WAR ----
        if constexpr (XT) {
            raw_bar();
            const int tn = d ? ((Sd - 2 - t) > 0 ? (Sd - 2 - t) : 0)
                             : ((t + 1) < (Sd - 1) ? (t + 1) : (Sd - 1));
            stage_x(tn);   // clamped at last step: harmless reload, uniform vmcnt
        }

        // ---- h-part MFMAs from prefetched A; counted waits keep glds in flight ----
        f32x4 acc0 = xacc0, acc1 = xacc1;
        if constexpr (XT) asm volatile("s_waitcnt vmcnt(24)" ::: "memory");
        else              asm volatile("s_waitcnt vmcnt(16)" ::: "memory");
        __builtin_amdgcn_sched_barrier(0);
        #pragma unroll
        for (int kb = 0; kb < 16; ++kb)
            acc0 = __builtin_amdgcn_mfma_f32_16x16x32_bf16(A0[kb], Bfrag[kb], acc0, 0, 0, 0);
        __builtin_amdgcn_sched_barrier(0);
        if constexpr (XT) asm volatile("s_waitcnt vmcnt(8)" ::: "memory");
        else              asm volatile("s_waitcnt vmcnt(0)" ::: "memory");
        __builtin_amdgcn_sched_barrier(0);
        #pragma unroll
        for (int kb = 0; kb < 16; ++kb)
            acc1 = __builtin_amdgcn_mfma_f32_16x16x32_bf16(A1[kb], Bfrag[kb], acc1, 0, 0, 0);

        // ---- scatter preacts to LDS ----
        {
            const int nl = wid * 16 + (lane & 15);
            const int mr = (lane >> 4) * 4;
            #pragma unroll
            for (int r = 0; r < 4; ++r) gbuf[(mr + r) * 64 + nl] = acc0[r];
            #pragma unroll
            for (int r = 0; r < 4; ++r) gbuf[(16 + mr + r) * 64 + nl] = acc1[r];
        }
        lgkm_bar();

        // ---- combine: activations + c/h update ----
        float h0c, h1c;
        {
            const f32x4 ga = *(const f32x4*)&gbuf[mloc * 64 + jloc * 4];
            const f32x4 gb = *(const f32x4*)&gbuf[(mloc + 16) * 64 + jloc * 4];
            c0 = c0 * sigmoidf_(ga[0] + bf_) + tanhf_(ga[1] + bg_) * sigmoidf_(ga[2] + bi_);
            h0c = sigmoidf_(ga[3] + bo_) * tanhf_(c0);
            c1 = c1 * sigmoidf_(gb[0] + bf_) + tanhf_(gb[1] + bg_) * sigmoidf_(gb[2] + bi_);
            h1c = sigmoidf_(gb[3] + bo_) * tanhf_(c1);
            hbuf[mloc * 16 + jloc] = h0c;
            hbuf[(mloc + 16) * 16 + jloc] = h1c;
        }
        lgkm_bar();

        if (t < Sd - 1) {
            // ---- producer (wave 0): pack -> coherent store -> ack -> flag ----
            if (tid < 64) {
                const int ml2 = tid >> 1;
                const int jh  = tid & 1;
                const int b   = mhalf * 32 + ml2;
                const int jb  = ng * 16 + jh * 8;
                const int kb  = jb >> 5;
                const int lq  = (jb >> 3) & 3;
                const int lh  = (b & 15) + lq * 16;
                const int mt  = b >> 4;
                const float* hp4 = &hbuf[ml2 * 16 + jh * 8];
                bf16x8 v;
                unsigned* vu = (unsigned*)&v;
                vu[0] = cvt_pk_bf16(hp4[0], hp4[1]);
                vu[1] = cvt_pk_bf16(hp4[2], hp4[3]);
                vu[2] = cvt_pk_bf16(hp4[4], hp4[5]);
                vu[3] = cvt_pk_bf16(hp4[6], hp4[7]);
                bf16x8* hp = hbf_w + (size_t)(((p1 * 2 + d) * 4 + mt) * 16 + kb) * 64 + lh;
                asm volatile("global_store_dwordx4 %0, %1, off sc0 sc1"
                             :: "v"(hp), "v"(v) : "memory");
                asm volatile("s_waitcnt vmcnt(0)" ::: "memory");   // h acked
                if (tid == 0) {
                    unsigned* fp = flg + ng;
                    const unsigned fv = (unsigned)(t + 1);
                    asm volatile("global_store_dword %0, %1, off sc0 sc1"
                                 :: "v"(fp), "v"(fv) : "memory");
                }
            }
            // ---- poll (all waves): all 32 flags in one load + ballot, watchdog ----
            {
                const unsigned tgt = (unsigned)(t + 1);
                const unsigned* fp = flg + (lane & 31);
                int guard = 0;
                for (;;) {
                    unsigned v;
                    asm volatile("global_load_dword %0, %1, off sc0 sc1\n\t"
                                 "s_waitcnt vmcnt(0)"
                                 : "=v"(v) : "v"(fp) : "memory");
                    if (__ballot(v >= tgt) == ~0ull) break;
                    __builtin_amdgcn_s_sleep(1);
                    if (++guard > (1 << 15)) break;   // fail loud, never wedge
                }
                __builtin_amdgcn_sched_barrier(0);
            }
        }

        // ---- output stores (off the sync critical path) ----
        {
            const int b0 = mhalf * 32 + mloc;
            const int jg = ng * 16 + jloc;
            float* ob = out + (size_t)d * Hd + jg;
            __builtin_nontemporal_store(h0c, ob + ((size_t)t_orig * Bd + b0) * TWO_H);
            __builtin_nontemporal_store(h1c, ob + ((size_t)t_orig * Bd + b0 + 16) * TWO_H);
            if (t == Sd - 1) {
                float* hf = out + (size_t)Sd * Bd * TWO_H + (size_t)d * Bd * Hd + jg;
                hf[(size_t)b0 * Hd] = h0c;
                hf[(size_t)(b0 + 16) * Hd] = h1c;
            }
        }

        if (t == Sd - 1) break;

        // ---- issue h(t+1) prefetch (consumed at next top's counted waits) ----
        issue_h(p1);

        // ---- x path: finish x(t+1) tile, then x-MFMA (hides h RTT) ----
        if constexpr (XT) {
            // queue: [8 glds old, done][2 out][32 h new] -> vmcnt(32) drains out+glds
            asm volatile("s_waitcnt vmcnt(32)" ::: "memory");
            __builtin_amdgcn_sched_barrier(0);
            raw_bar();
        } else {
            const int tn = d ? (Sd - 2 - t) : (t + 1);
            stage_x_conv(tn);
            lgkm_bar();
        }
        xmfma();
    }
}

extern "C" void kernel_launch(void* const* d_in, const int* in_sizes, int n_in,
                              void* d_out, int out_size, void* d_ws, size_t ws_size,
                              hipStream_t stream) {
    const float* x   = (const float*)d_in[0];
    // d_in[1] = mask: all-ones by construction; unused.
    const float* U_f = (const float*)d_in[2];
    const float* W_f = (const float*)d_in[3];
    const float* b_f = (const float*)d_in[4];
    const float* U_b = (const float*)d_in[5];
    const float* W_b = (const float*)d_in[6];
    const float* b_b = (const float*)d_in[7];
    float* out = (float*)d_out;
    unsigned char* ws = (unsigned char*)d_ws;

    prep_weights<<<2048, 256, 0, stream>>>(U_f, W_f, U_b, W_b,
                                           (unsigned short*)(ws + UWT_OFF));
    prep_misc<<<64, 256, 0, stream>>>(b_f, b_b, ws);

    if (ws_size >= (size_t)WS_NEED) {
        prep_x<<<8192, 256, 0, stream>>>(x, (unsigned short*)(ws + XT_OFF));
        lstm_persist<true><<<128, 256, 0, stream>>>(x, ws, out);
    } else {
        lstm_persist<false><<<128, 256, 0, stream>>>(x, ws, out);
    }
}